// Round 13
// baseline (1453.895 us; speedup 1.0000x reference)
//
#include <hip/hip_runtime.h>
#include <math.h>

#define DEV __device__ __forceinline__

static constexpr int B_ = 128, T_ = 32, H_ = 512;
static constexpr int S_ = 2048, M_ = 64, OUT_ = 256;
static constexpr float EPSF = 1e-8f;

DEV float sigmoidf_(float x){ return 1.0f/(1.0f+expf(-x)); }
DEV float softplusf_(float x){ return fmaxf(x,0.0f) + log1pf(expf(-fabsf(x))); }

// ---- packed candidate: (monotonic(value) << 32) | ~idx  => u64 '>' == (value desc, idx asc)
DEV unsigned long long packCand(float v, unsigned idx){
  unsigned u = __float_as_uint(v);
  unsigned m = (u & 0x80000000u) ? ~u : (u | 0x80000000u);
  return ((unsigned long long)m << 32) | (unsigned)(~idx);
}
DEV float unpackVal(unsigned long long e){
  unsigned m = (unsigned)(e >> 32);
  unsigned u = (m & 0x80000000u) ? (m & 0x7FFFFFFFu) : ~m;
  return __uint_as_float(u);
}
DEV unsigned unpackIdx(unsigned long long e){ return ~(unsigned)e; }

DEV void cswp(unsigned long long &a, unsigned long long &b){
  if(a < b){ unsigned long long t=a; a=b; b=t; }   // larger first (descending)
}
// Batcher odd-even mergesort for 8, descending
DEV void sort8(unsigned long long* L){
  cswp(L[0],L[1]); cswp(L[2],L[3]); cswp(L[4],L[5]); cswp(L[6],L[7]);
  cswp(L[0],L[2]); cswp(L[1],L[3]); cswp(L[4],L[6]); cswp(L[5],L[7]);
  cswp(L[1],L[2]); cswp(L[5],L[6]);
  cswp(L[0],L[4]); cswp(L[1],L[5]); cswp(L[2],L[6]); cswp(L[3],L[7]);
  cswp(L[2],L[4]); cswp(L[3],L[5]);
  cswp(L[1],L[2]); cswp(L[3],L[4]); cswp(L[5],L[6]);
}
// bitonic merge of 16, descending (input must be bitonic)
DEV void bmerge16(unsigned long long* C){
  #pragma unroll
  for(int i=0;i<8;i++) cswp(C[i],C[i+8]);
  #pragma unroll
  for(int g=0;g<2;g++){ int o=g*8;
    cswp(C[o+0],C[o+4]); cswp(C[o+1],C[o+5]); cswp(C[o+2],C[o+6]); cswp(C[o+3],C[o+7]); }
  #pragma unroll
  for(int g=0;g<4;g++){ int o=g*4; cswp(C[o+0],C[o+2]); cswp(C[o+1],C[o+3]); }
  #pragma unroll
  for(int g=0;g<8;g++){ int o=g*2; cswp(C[o],C[o+1]); }
}
// butterfly keep-8: each lane holds sorted-8 desc
DEV void butterfly8(unsigned long long* L, int maxMask){
  for(int mask=1; mask<=maxMask; mask<<=1){
    unsigned long long O[8], C[8];
    #pragma unroll
    for(int i=0;i<8;i++) O[i] = __shfl_xor(L[i], mask, 64);
    #pragma unroll
    for(int i=0;i<8;i++){ unsigned long long a=L[i], b=O[7-i]; C[i] = (a>b)?a:b; }
    cswp(C[0],C[4]); cswp(C[1],C[5]); cswp(C[2],C[6]); cswp(C[3],C[7]);
    cswp(C[0],C[2]); cswp(C[1],C[3]); cswp(C[4],C[6]); cswp(C[5],C[7]);
    cswp(C[0],C[1]); cswp(C[2],C[3]); cswp(C[4],C[5]); cswp(C[6],C[7]);
    #pragma unroll
    for(int i=0;i<8;i++) L[i]=C[i];
  }
}
// butterfly keep-16 over all 64 lanes (per-lane lists sorted-16 desc)
DEV void butterfly16(unsigned long long* L){
  for(int mask=1; mask<64; mask<<=1){
    unsigned long long O[16], C[16];
    #pragma unroll
    for(int i=0;i<16;i++) O[i] = __shfl_xor(L[i], mask, 64);
    #pragma unroll
    for(int i=0;i<16;i++){ unsigned long long a=L[i], b=O[15-i]; C[i] = (a>b)?a:b; }
    bmerge16(C);
    #pragma unroll
    for(int i=0;i<16;i++) L[i]=C[i];
  }
}

// ctrl partial-sum read: cp = ctrl partials (4 planes of 128x512) at current parity.
// value(jj) = sum_z cp[z][b][jj] + bhead[jj]   (jj = ctrl column - 256; jj < 453 valid)
DEV float ctrlv(const float* __restrict__ cp, int b, int jj, const float* __restrict__ bh){
  size_t o = (size_t)b*512 + jj;
  return cp[o] + cp[65536+o] + cp[131072+o] + cp[196608+o] + bh[jj];
}

// ---------------- pipeline launch 1 (256 thr, 608 blocks) ----------------
// blk 0..255  : gemmA(tG)    — gparts = h(tG-1) @ W_hh^T, split-K x4
// blk 256..319: ctrlcat(tV)  — ctrl partials (4 z-planes of [128][512]), split-K x4
// blk 320..447: heads(tH)    — write head + mem update + read heads -> reads_all
// blk 448..479: vt(tV)       — vt partials (4 z-planes of [128][256]), split-K x4
// blk 480..607: xgt(tG)      — xg partials for step tG (2 z-planes of [128][2048]), split-K x2
__global__ __launch_bounds__(256)
void k_L1(const float* __restrict__ hprev, const float* __restrict__ Whh,
          float* __restrict__ gparts, int tG,
          const float* __restrict__ hv,
          const float* __restrict__ Wout, const float* __restrict__ Whead,
          float* __restrict__ ctrlW, float* __restrict__ vtpW, int tV,
          float* __restrict__ memC, const float* __restrict__ ctrlH,
          const float* __restrict__ bhead,
          const unsigned long long* __restrict__ candW,
          const unsigned long long* __restrict__ candR,
          const float* __restrict__ statsB,
          float* __restrict__ readsAll, int tH,
          const float* __restrict__ x, const float* __restrict__ Wih,
          const float* __restrict__ bih, const float* __restrict__ bhh,
          float* __restrict__ xgp)
{
  __shared__ __align__(16) float smem[2304];
  const int blk = blockIdx.x, tid = threadIdx.x;

  if(blk < 256){
    // ---- gemmA role (round-12-verified) ----
    if(tG < 0) return;
    float* As = smem;
    float* Bs = smem + 1088;
    const int z = blk >> 6, rem = blk & 63;
    const int m0 = (rem & 1)*64, n0 = (rem >> 1)*64;
    const int tx = tid & 15, ty = tid >> 4;
    float acc[4][4] = {};
    const int row = tid >> 2, kq = (tid & 3)*4;
    const int kStart = z*128;
    for(int k0 = kStart; k0 < kStart + 128; k0 += 16){
      float4 av = *(const float4*)(hprev + (size_t)(m0+row)*512 + k0 + kq);
      float4 bv = *(const float4*)(Whh   + (size_t)(n0+row)*512 + k0 + kq);
      As[(kq+0)*68+row]=av.x; As[(kq+1)*68+row]=av.y; As[(kq+2)*68+row]=av.z; As[(kq+3)*68+row]=av.w;
      Bs[(kq+0)*68+row]=bv.x; Bs[(kq+1)*68+row]=bv.y; Bs[(kq+2)*68+row]=bv.z; Bs[(kq+3)*68+row]=bv.w;
      __syncthreads();
      #pragma unroll
      for(int k=0;k<16;k++){
        float4 a = *(const float4*)&As[k*68 + 4*ty];
        float4 b = *(const float4*)&Bs[k*68 + 4*tx];
        acc[0][0]+=a.x*b.x; acc[0][1]+=a.x*b.y; acc[0][2]+=a.x*b.z; acc[0][3]+=a.x*b.w;
        acc[1][0]+=a.y*b.x; acc[1][1]+=a.y*b.y; acc[1][2]+=a.y*b.z; acc[1][3]+=a.y*b.w;
        acc[2][0]+=a.z*b.x; acc[2][1]+=a.z*b.y; acc[2][2]+=a.z*b.z; acc[2][3]+=a.z*b.w;
        acc[3][0]+=a.w*b.x; acc[3][1]+=a.w*b.y; acc[3][2]+=a.w*b.z; acc[3][3]+=a.w*b.w;
      }
      __syncthreads();
    }
    float* Cz = gparts + (size_t)z*262144;
    #pragma unroll
    for(int i=0;i<4;i++){
      float4 o; o.x=acc[i][0]; o.y=acc[i][1]; o.z=acc[i][2]; o.w=acc[i][3];
      *(float4*)(Cz + (size_t)(m0+4*ty+i)*2048 + n0 + 4*tx) = o;
    }
    return;
  }

  if(blk < 320){
    // ---- ctrlcat role: ctrl partials, split-K x4 (no bias; consumer adds bhead) ----
    if(tV < 0) return;
    float* As = smem;
    float* Bs = smem + 1088;
    const int g = blk - 256;                 // 0..63
    const int z = g >> 4, rem = g & 15;
    const int m0 = (rem & 1)*64;
    const int jj0 = (rem >> 1)*64;           // ctrl-local col base (0..448)
    const int tx = tid & 15, ty = tid >> 4;
    float acc[4][4] = {};
    const int row = tid >> 2, kq = (tid & 3)*4;
    const int kStart = z*128;
    const int jr = jj0 + row;
    const float* Bsrc = (jr < 453) ? (Whead + (size_t)jr*512) : nullptr;
    for(int k0 = kStart; k0 < kStart + 128; k0 += 16){
      float4 av = *(const float4*)(hv + (size_t)(m0+row)*512 + k0 + kq);
      float4 bv = make_float4(0.f,0.f,0.f,0.f);
      if(Bsrc) bv = *(const float4*)(Bsrc + k0 + kq);
      As[(kq+0)*68+row]=av.x; As[(kq+1)*68+row]=av.y; As[(kq+2)*68+row]=av.z; As[(kq+3)*68+row]=av.w;
      Bs[(kq+0)*68+row]=bv.x; Bs[(kq+1)*68+row]=bv.y; Bs[(kq+2)*68+row]=bv.z; Bs[(kq+3)*68+row]=bv.w;
      __syncthreads();
      #pragma unroll
      for(int k=0;k<16;k++){
        float4 a = *(const float4*)&As[k*68 + 4*ty];
        float4 b = *(const float4*)&Bs[k*68 + 4*tx];
        acc[0][0]+=a.x*b.x; acc[0][1]+=a.x*b.y; acc[0][2]+=a.x*b.z; acc[0][3]+=a.x*b.w;
        acc[1][0]+=a.y*b.x; acc[1][1]+=a.y*b.y; acc[1][2]+=a.y*b.z; acc[1][3]+=a.y*b.w;
        acc[2][0]+=a.z*b.x; acc[2][1]+=a.z*b.y; acc[2][2]+=a.z*b.z; acc[2][3]+=a.z*b.w;
        acc[3][0]+=a.w*b.x; acc[3][1]+=a.w*b.y; acc[3][2]+=a.w*b.z; acc[3][3]+=a.w*b.w;
      }
      __syncthreads();
    }
    float* Cz = ctrlW + (size_t)z*65536;     // z-plane: 128*512
    #pragma unroll
    for(int i=0;i<4;i++){
      float4 o; o.x=acc[i][0]; o.y=acc[i][1]; o.z=acc[i][2]; o.w=acc[i][3];
      *(float4*)(Cz + (size_t)(m0+4*ty+i)*512 + jj0 + 4*tx) = o;
    }
    return;
  }

  if(blk < 448){
    // ---- heads role (round-12-verified body) ----
    if(tH < 0) return;
    float* kr     = smem;                    // 256 (16B-aligned)
    float* nv     = smem + 256;              // 512
    float* oldrow = smem + 768;              // 512
    float* er     = smem + 1280;             // 64
    float* ad     = smem + 1344;             // 64
    float* coefR  = smem + 1408;             // 4
    int*   widx   = (int*)(smem + 1412);     // 8
    float* wval   = smem + 1420;             // 8

    const int b = blk - 320;
    const int lane = tid & 63, wave = tid >> 6;
    const size_t memb = (size_t)b*(size_t)S_*M_;

    kr[tid] = tanhf(ctrlv(ctrlH, b, tid, bhead));                    // v[256+tid]
    if(tid < 64){
      er[tid] = sigmoidf_(ctrlv(ctrlH, b, 325+tid, bhead));          // v[581+tid]
      ad[tid] = tanhf(ctrlv(ctrlH, b, 389+tid, bhead));              // v[645+tid]
    }
    __syncthreads();

    if(wave == 0){
      float smx[4], ssm[4];
      #pragma unroll
      for(int c2=0;c2<4;c2++){
        const float* st = statsB + (((size_t)b*4 + c2)*5 + 4)*2;
        smx[c2] = st[0]; ssm[c2] = st[1];
      }
      float mxw = fmaxf(fmaxf(smx[0],smx[1]), fmaxf(smx[2],smx[3]));
      float Zw = ssm[0]*expf(smx[0]-mxw) + ssm[1]*expf(smx[1]-mxw)
               + ssm[2]*expf(smx[2]-mxw) + ssm[3]*expf(smx[3]-mxw);
      unsigned long long L[8];
      L[0] = (lane < 32) ? candW[((size_t)b*4 + (lane>>3))*8 + (lane&7)] : 0ULL;
      #pragma unroll
      for(int j=1;j<8;j++) L[j] = 0ULL;
      butterfly8(L, 16);
      if(lane == 0){
        float invZ = 1.0f / Zw;
        #pragma unroll
        for(int p=0;p<8;p++){
          widx[p] = (int)unpackIdx(L[p]);
          wval[p] = expf(unpackVal(L[p]) - mxw) * invZ;
        }
      }
    } else if(wave == 1 && lane < 4){
      float s = 0.f;
      #pragma unroll
      for(int m=0;m<64;m++){ float x2 = kr[lane*64+m]; s += x2*x2; }
      coefR[lane] = softplusf_(ctrlv(ctrlH, b, 256+lane, bhead)) / fmaxf(sqrtf(s), EPSF);
    }
    __syncthreads();

    {
      #pragma unroll
      for(int p=0;p<2;p++){
        int idx = tid + p*256;
        int jj = idx >> 6, mm = idx & 63;
        int s = widx[jj];
        float w = wval[jj];
        size_t ptr = memb + (size_t)s*M_ + mm;
        float old = memC[ptr];
        oldrow[jj*64+mm] = old;
        float x2 = old * (1.0f - w*er[mm]) + w*ad[mm];
        memC[ptr] = x2;
        nv[jj*64+mm] = x2;
      }
    }
    __syncthreads();

    {
      const int r = wave;
      const int sW = lane & 7, g = lane >> 3;
      const float4* nv4 = (const float4*)nv;
      const float4* ov4 = (const float4*)oldrow;
      const float4* kr4 = (const float4*)kr;
      float4 na = nv4[sW*16 + g*2], nb2 = nv4[sW*16 + g*2 + 1];
      float4 oa = ov4[sW*16 + g*2], ob = ov4[sW*16 + g*2 + 1];
      float4 ka = kr4[r*16  + g*2], kb = kr4[r*16  + g*2 + 1];
      float dot = na.x*ka.x + na.y*ka.y + na.z*ka.z + na.w*ka.w
                + nb2.x*kb.x + nb2.y*kb.y + nb2.z*kb.z + nb2.w*kb.w;
      float n2  = na.x*na.x + na.y*na.y + na.z*na.z + na.w*na.w
                + nb2.x*nb2.x + nb2.y*nb2.y + nb2.z*nb2.z + nb2.w*nb2.w;
      float odot= oa.x*ka.x + oa.y*ka.y + oa.z*ka.z + oa.w*ka.w
                + ob.x*kb.x + ob.y*kb.y + ob.z*kb.z + ob.w*kb.w;
      float on2 = oa.x*oa.x + oa.y*oa.y + oa.z*oa.z + oa.w*oa.w
                + ob.x*ob.x + ob.y*ob.y + ob.z*ob.z + ob.w*ob.w;
      #pragma unroll
      for(int mask=8; mask<64; mask<<=1){
        dot  += __shfl_xor(dot,  mask, 64);
        n2   += __shfl_xor(n2,   mask, 64);
        odot += __shfl_xor(odot, mask, 64);
        on2  += __shfl_xor(on2,  mask, 64);
      }
      float fixv = coefR[r] * dot  / fmaxf(sqrtf(n2),  EPSF);
      float oldv = coefR[r] * odot / fmaxf(sqrtf(on2), EPSF);
      int myw = widx[sW];

      float scx[4], scs[4];
      #pragma unroll
      for(int c2=0;c2<4;c2++){
        const float* st = statsB + (((size_t)b*4 + c2)*5 + r)*2;
        scx[c2] = st[0]; scs[c2] = st[1];
      }
      float mxp = fmaxf(fmaxf(scx[0],scx[1]), fmaxf(scx[2],scx[3]));

      unsigned long long L[8];
      {
        int c2 = lane >> 4, rank = lane & 15;
        unsigned long long eA = candR[(((size_t)b*4 + c2)*4 + r)*16 + rank];
        unsigned idxA = unpackIdx(eA);
        bool kill = false;
        #pragma unroll
        for(int p=0;p<8;p++) kill = kill || (idxA == (unsigned)widx[p]);
        if(kill) eA = 0ULL;
        unsigned long long eB = (lane < 8) ? packCand(fixv, (unsigned)myw) : 0ULL;
        L[0] = (eA > eB) ? eA : eB;
        L[1] = (eA > eB) ? eB : eA;
        #pragma unroll
        for(int j2=2;j2<8;j2++) L[j2] = 0ULL;
      }
      butterfly8(L, 32);

      float mxS = fmaxf(mxp, unpackVal(L[0]));
      float Zp = scs[0]*expf(scx[0]-mxS) + scs[1]*expf(scx[1]-mxS)
               + scs[2]*expf(scx[2]-mxS) + scs[3]*expf(scx[3]-mxS);
      float adj = (lane < 8) ? (expf(fixv - mxS) - expf(oldv - mxS)) : 0.f;
      #pragma unroll
      for(int mask=1; mask<64; mask<<=1) adj += __shfl_xor(adj, mask, 64);
      float invZ = 1.0f / (Zp + adj);

      float acc = 0.f;
      #pragma unroll
      for(int p=0;p<8;p++){
        float w = expf(unpackVal(L[p]) - mxS) * invZ;
        int si = (int)unpackIdx(L[p]);
        acc += w * memC[memb + (size_t)si*M_ + lane];
      }
      readsAll[((size_t)b*T_ + tH)*256 + r*64 + lane] = acc;
    }
    return;
  }

  if(blk < 480){
    // ---- vt role: vt partials, split-K x4 (no bias; vtsum adds bout) ----
    if(tV < 0) return;
    float* As = smem;
    float* Bs = smem + 1088;
    const int g = blk - 448;                 // 0..31
    const int z = g >> 3, rem = g & 7;
    const int m0 = (rem & 1)*64, n0 = (rem >> 1)*64;
    const int tx = tid & 15, ty = tid >> 4;
    float acc[4][4] = {};
    const int row = tid >> 2, kq = (tid & 3)*4;
    const int kStart = z*128;
    const float* Bsrc = Wout + (size_t)(n0+row)*512;
    for(int k0 = kStart; k0 < kStart + 128; k0 += 16){
      float4 av = *(const float4*)(hv + (size_t)(m0+row)*512 + k0 + kq);
      float4 bv = *(const float4*)(Bsrc + k0 + kq);
      As[(kq+0)*68+row]=av.x; As[(kq+1)*68+row]=av.y; As[(kq+2)*68+row]=av.z; As[(kq+3)*68+row]=av.w;
      Bs[(kq+0)*68+row]=bv.x; Bs[(kq+1)*68+row]=bv.y; Bs[(kq+2)*68+row]=bv.z; Bs[(kq+3)*68+row]=bv.w;
      __syncthreads();
      #pragma unroll
      for(int k=0;k<16;k++){
        float4 a = *(const float4*)&As[k*68 + 4*ty];
        float4 b = *(const float4*)&Bs[k*68 + 4*tx];
        acc[0][0]+=a.x*b.x; acc[0][1]+=a.x*b.y; acc[0][2]+=a.x*b.z; acc[0][3]+=a.x*b.w;
        acc[1][0]+=a.y*b.x; acc[1][1]+=a.y*b.y; acc[1][2]+=a.y*b.z; acc[1][3]+=a.y*b.w;
        acc[2][0]+=a.z*b.x; acc[2][1]+=a.z*b.y; acc[2][2]+=a.z*b.z; acc[2][3]+=a.z*b.w;
        acc[3][0]+=a.w*b.x; acc[3][1]+=a.w*b.y; acc[3][2]+=a.w*b.z; acc[3][3]+=a.w*b.w;
      }
      __syncthreads();
    }
    float* Cz = vtpW + (size_t)z*32768;      // z-plane: 128*256
    #pragma unroll
    for(int i=0;i<4;i++){
      float4 o; o.x=acc[i][0]; o.y=acc[i][1]; o.z=acc[i][2]; o.w=acc[i][3];
      *(float4*)(Cz + (size_t)(m0+4*ty+i)*256 + n0 + 4*tx) = o;
    }
    return;
  }

  // ---- xgt role: xg partials for step tG, split-K x2 (z=0 plane adds bias) ----
  if(tG < 0) return;
  {
    float* As = smem;
    float* Bs = smem + 1088;
    const int g = blk - 480;                 // 0..127
    const int z = g >> 6, rem = g & 63;
    const int mb = (rem & 1)*64;             // batch base
    const int n0 = (rem >> 1)*64;            // gate-col base
    const int tx = tid & 15, ty = tid >> 4;
    float acc[4][4] = {};
    const int row = tid >> 2, kq = (tid & 3)*4;
    const int kStart = z*128;
    for(int k0 = kStart; k0 < kStart + 128; k0 += 16){
      float4 av = *(const float4*)(x   + ((size_t)(mb+row)*T_ + tG)*256 + k0 + kq);
      float4 bv = *(const float4*)(Wih + (size_t)(n0+row)*256 + k0 + kq);
      As[(kq+0)*68+row]=av.x; As[(kq+1)*68+row]=av.y; As[(kq+2)*68+row]=av.z; As[(kq+3)*68+row]=av.w;
      Bs[(kq+0)*68+row]=bv.x; Bs[(kq+1)*68+row]=bv.y; Bs[(kq+2)*68+row]=bv.z; Bs[(kq+3)*68+row]=bv.w;
      __syncthreads();
      #pragma unroll
      for(int k=0;k<16;k++){
        float4 a = *(const float4*)&As[k*68 + 4*ty];
        float4 b = *(const float4*)&Bs[k*68 + 4*tx];
        acc[0][0]+=a.x*b.x; acc[0][1]+=a.x*b.y; acc[0][2]+=a.x*b.z; acc[0][3]+=a.x*b.w;
        acc[1][0]+=a.y*b.x; acc[1][1]+=a.y*b.y; acc[1][2]+=a.y*b.z; acc[1][3]+=a.y*b.w;
        acc[2][0]+=a.z*b.x; acc[2][1]+=a.z*b.y; acc[2][2]+=a.z*b.z; acc[2][3]+=a.z*b.w;
        acc[3][0]+=a.w*b.x; acc[3][1]+=a.w*b.y; acc[3][2]+=a.w*b.z; acc[3][3]+=a.w*b.w;
      }
      __syncthreads();
    }
    const int nb = n0 + 4*tx;
    float bias[4] = {0.f,0.f,0.f,0.f};
    if(z == 0){
      #pragma unroll
      for(int j2=0;j2<4;j2++){ int n = nb + j2; bias[j2] = bih[n] + bhh[n]; }
    }
    float* Cz = xgp + (size_t)z*262144;      // z-plane: 128*2048
    #pragma unroll
    for(int i=0;i<4;i++){
      float4 o; o.x=acc[i][0]+bias[0]; o.y=acc[i][1]+bias[1];
      o.z=acc[i][2]+bias[2]; o.w=acc[i][3]+bias[3];
      *(float4*)(Cz + (size_t)(mb+4*ty+i)*2048 + nb) = o;
    }
  }
}

// ---------------- pipeline launch 2 (512 thr, 704 blocks) ----------------
// blk 0..511  : scores(tS) — round-12-verified body, v[] via ctrl partial sum
// blk 512..639: lstm(tL)   — gate sum (2 xg planes + 4 gparts planes) + cell update -> hout
// blk 640..703: vtsum(tS)  — out[b,tS,:] = sum_z vtp[z] + bout
__global__ __launch_bounds__(512)
void k_L2(const float* __restrict__ xgp, const float* __restrict__ gp,
          float* __restrict__ hout, float* __restrict__ c, int tL,
          const float* __restrict__ memC, const float* __restrict__ ctrlS,
          const float* __restrict__ bhead,
          unsigned long long* __restrict__ candW,
          unsigned long long* __restrict__ candR,
          float* __restrict__ statsB, int tS,
          const float* __restrict__ vtpR, const float* __restrict__ bout,
          float* __restrict__ out)
{
  __shared__ float smem[2896];
  const int blk = blockIdx.x, tid = threadIdx.x;

  if(blk >= 640){
    // ---- vtsum role ----
    if(tS < 0) return;
    int idx = (blk - 640)*512 + tid;         // 0..32767
    int b = idx >> 8, n = idx & 255;
    float s = vtpR[(size_t)b*256+n] + vtpR[32768 + (size_t)b*256+n]
            + vtpR[65536 + (size_t)b*256+n] + vtpR[98304 + (size_t)b*256+n];
    out[((size_t)b*T_ + tS)*OUT_ + n] = s + bout[n];
    return;
  }
  if(blk >= 512){
    // ---- lstm role (xg from 2 split-K partial planes) ----
    if(tL < 0) return;
    int idx = (blk - 512)*512 + tid;         // 0..65535
    int b = idx >> 9, j = idx & 511;
    const float* x0 = xgp + (size_t)b*2048;
    const float* x1 = xgp + 262144 + (size_t)b*2048;
    float gi = x0[j]      + x1[j];
    float gf = x0[512+j]  + x1[512+j];
    float gg = x0[1024+j] + x1[1024+j];
    float go = x0[1536+j] + x1[1536+j];
    #pragma unroll
    for(int s4=0;s4<4;s4++){
      const float* pr = gp + ((size_t)s4*B_ + b)*(size_t)(4*H_);
      gi += pr[j]; gf += pr[512+j]; gg += pr[1024+j]; go += pr[1536+j];
    }
    float cc = sigmoidf_(gf)*c[idx] + sigmoidf_(gi)*tanhf(gg);
    float hh = sigmoidf_(go)*tanhf(cc);
    c[idx] = cc; hout[idx] = hh;
    return;
  }

  // ---- scores role ----
  if(tS < 0) return;
  float* kk   = smem;          // 320
  float* coef = smem + 320;    // 8 (5 used)
  float* tile = smem + 328;    // 5*512
  const int b = blk >> 2, ch = blk & 3;
  const int lane = tid & 63, wid = tid >> 6;
  if(tid < 256) kk[tid] = tanhf(ctrlv(ctrlS, b, tid, bhead));          // kr: v[256+tid]
  else if(tid < 320) kk[tid] = tanhf(ctrlv(ctrlS, b, tid+4, bhead));   // kw: jj = 260..323
  __syncthreads();
  if(tid < 5){
    float s = 0.f;
    #pragma unroll
    for(int m=0;m<64;m++){ float x2 = kk[tid*64+m]; s += x2*x2; }
    float beta = softplusf_( tid<4 ? ctrlv(ctrlS, b, 256+tid, bhead)
                                   : ctrlv(ctrlS, b, 324, bhead) );
    coef[tid] = beta / fmaxf(sqrtf(s), EPSF);
  }
  __syncthreads();

  {
    const int s = ch*512 + tid;
    const float4* row = (const float4*)(memC + ((size_t)b*S_ + s)*M_);
    float nrm=0.f, d0=0.f, d1=0.f, d2=0.f, d3=0.f, dw=0.f;
    #pragma unroll
    for(int r4=0;r4<16;r4++){
      float4 xa = row[r4];
      float av[4] = {xa.x,xa.y,xa.z,xa.w};
      #pragma unroll
      for(int j=0;j<4;j++){
        const int m = r4*4+j;
        float a = av[j];
        nrm += a*a;
        d0 += a*kk[m];     d1 += a*kk[64+m]; d2 += a*kk[128+m];
        d3 += a*kk[192+m]; dw += a*kk[256+m];
      }
    }
    float inv = 1.0f / fmaxf(sqrtf(nrm), EPSF);
    tile[0*512+tid] = coef[0]*d0*inv;
    tile[1*512+tid] = coef[1]*d1*inv;
    tile[2*512+tid] = coef[2]*d2*inv;
    tile[3*512+tid] = coef[3]*d3*inv;
    tile[4*512+tid] = coef[4]*dw*inv;
  }
  __syncthreads();

  if(wid < 4){
    unsigned long long L[16];
    #pragma unroll
    for(int j=0;j<8;j++){
      int i = lane + j*64;
      L[j] = packCand(tile[wid*512 + i], (unsigned)(ch*512 + i));
    }
    sort8(L);
    #pragma unroll
    for(int j=8;j<16;j++) L[j] = 0ULL;
    butterfly16(L);
    if(lane == 0){
      unsigned long long* dst = candR + (((size_t)b*4 + ch)*4 + wid)*16;
      #pragma unroll
      for(int j=0;j<16;j++) dst[j] = L[j];
    }
  } else if(wid == 4){
    unsigned long long L[8];
    #pragma unroll
    for(int j=0;j<8;j++){
      int i = lane + j*64;
      L[j] = packCand(tile[4*512 + i], (unsigned)(ch*512 + i));
    }
    sort8(L);
    butterfly8(L, 32);
    if(lane == 0){
      unsigned long long* dst = candW + ((size_t)b*4 + ch)*8;
      #pragma unroll
      for(int j=0;j<8;j++) dst[j] = L[j];
    }
  } else {
    int h0 = (wid==5) ? 0 : (wid==6) ? 2 : 4;
    int nh = (wid==7) ? 1 : 2;
    for(int q=0;q<nh;q++){
      int h = h0 + q;
      float x2[8];
      #pragma unroll
      for(int j=0;j<8;j++) x2[j] = tile[h*512 + lane + j*64];
      float mx = x2[0];
      #pragma unroll
      for(int j=1;j<8;j++) mx = fmaxf(mx, x2[j]);
      #pragma unroll
      for(int mask=1; mask<64; mask<<=1) mx = fmaxf(mx, __shfl_xor(mx, mask, 64));
      float sm = 0.f;
      #pragma unroll
      for(int j=0;j<8;j++) sm += expf(x2[j]-mx);
      #pragma unroll
      for(int mask=1; mask<64; mask<<=1) sm += __shfl_xor(sm, mask, 64);
      if(lane == 0){
        float* st = statsB + (((size_t)b*4 + ch)*5 + h)*2;
        st[0] = mx; st[1] = sm;
      }
    }
  }
}

// ---------------- final: out += reads_all @ W_rd^T + b_rd  (vt already in out) ----------------
__global__ __launch_bounds__(256)
void k_outg(const float* __restrict__ A,             // reads_all [4096,256]
            const float* __restrict__ Wrd,           // [256,256]
            const float* __restrict__ brd,
            float* __restrict__ out)
{
  const int BK=16, LDT=68;
  __shared__ float As[BK*LDT];
  __shared__ float Bs[BK*LDT];
  const int m0 = blockIdx.x*64, n0 = blockIdx.y*64;
  const int tid = threadIdx.x;
  const int tx = tid & 15, ty = tid >> 4;
  float acc[4][4] = {};
  const int row = tid >> 2, kk = (tid & 3) * 4;
  for(int k0 = 0; k0 < 256; k0 += BK){
    float4 av = *(const float4*)(A   + (size_t)(m0+row)*256 + k0 + kk);
    float4 bv = *(const float4*)(Wrd + (size_t)(n0+row)*256 + k0 + kk);
    As[(kk+0)*LDT+row]=av.x; As[(kk+1)*LDT+row]=av.y; As[(kk+2)*LDT+row]=av.z; As[(kk+3)*LDT+row]=av.w;
    Bs[(kk+0)*LDT+row]=bv.x; Bs[(kk+1)*LDT+row]=bv.y; Bs[(kk+2)*LDT+row]=bv.z; Bs[(kk+3)*LDT+row]=bv.w;
    __syncthreads();
    #pragma unroll
    for(int k=0;k<BK;k++){
      float4 a = *(const float4*)&As[k*LDT + 4*ty];
      float4 b = *(const float4*)&Bs[k*LDT + 4*tx];
      acc[0][0]+=a.x*b.x; acc[0][1]+=a.x*b.y; acc[0][2]+=a.x*b.z; acc[0][3]+=a.x*b.w;
      acc[1][0]+=a.y*b.x; acc[1][1]+=a.y*b.y; acc[1][2]+=a.y*b.z; acc[1][3]+=a.y*b.w;
      acc[2][0]+=a.z*b.x; acc[2][1]+=a.z*b.y; acc[2][2]+=a.z*b.z; acc[2][3]+=a.z*b.w;
      acc[3][0]+=a.w*b.x; acc[3][1]+=a.w*b.y; acc[3][2]+=a.w*b.z; acc[3][3]+=a.w*b.w;
    }
    __syncthreads();
  }
  const int nb = n0 + 4*tx;
  float4 bb = *(const float4*)(brd + nb);
  #pragma unroll
  for(int i=0;i<4;i++){
    int m = m0 + 4*ty + i;
    float4 vt = *(const float4*)(out + (size_t)m*256 + nb);
    float4 o;
    o.x = acc[i][0] + bb.x + vt.x;
    o.y = acc[i][1] + bb.y + vt.y;
    o.z = acc[i][2] + bb.z + vt.z;
    o.w = acc[i][3] + bb.w + vt.w;
    *(float4*)(out + (size_t)m*256 + nb) = o;
  }
}

// ---------------- host ----------------
extern "C" void kernel_launch(void* const* d_in, const int* in_sizes, int n_in,
                              void* d_out, int out_size, void* d_ws, size_t ws_size,
                              hipStream_t stream)
{
  const float* x     = (const float*)d_in[0];
  const float* h0    = (const float*)d_in[1];
  const float* c0    = (const float*)d_in[2];
  const float* mem0  = (const float*)d_in[3];
  const float* W_ih  = (const float*)d_in[4];
  const float* W_hh  = (const float*)d_in[5];
  const float* b_ih  = (const float*)d_in[6];
  const float* b_hh  = (const float*)d_in[7];
  const float* W_out = (const float*)d_in[8];
  const float* b_out = (const float*)d_in[9];
  const float* W_rd  = (const float*)d_in[10];
  const float* b_rd  = (const float*)d_in[11];
  const float* W_head= (const float*)d_in[12];
  const float* b_head= (const float*)d_in[13];
  // d_in[14] = K (int) — fixed at 8 by the problem setup; hard-coded in k_L1 heads role.
  float* out = (float*)d_out;

  float* ws     = (float*)d_ws;
  float* memC   = ws;                    // 16,777,216  (slot-major [B,S,M])
  float* xgp    = memC  + 16777216;      //    524,288  (2 z-planes x 128 x 2048, per-step)
  float* hbuf   = xgp   + 524288;        //    131,072  (h ping-pong x2)
  float* c      = hbuf  + 131072;        //     65,536
  float* gparts = c     + 65536;         //  1,048,576
  float* ctrlP  = gparts+ 1048576;       //    524,288  (2 parity x 4 z x 128 x 512)
  float* vtp    = ctrlP + 524288;        //    262,144  (2 parity x 4 z x 128 x 256)
  float* reads_all = vtp + 262144;       //  1,048,576
  unsigned long long* candW = (unsigned long long*)(reads_all + 1048576); // 4096 u64
  unsigned long long* candR = candW + 4096;                               // 32768 u64
  float* statsB = (float*)(candR + 32768);                                // 5,120
  const size_t need = (size_t)(20460544) * sizeof(float);
  if(ws_size < need) return;  // ~81.8 MB workspace

  hipMemcpyAsync(c, c0, 65536*sizeof(float), hipMemcpyDeviceToDevice, stream);
  hipMemcpyAsync(memC, mem0, (size_t)16777216*sizeof(float), hipMemcpyDeviceToDevice, stream);

  // ---- 2-deep software pipeline over the two independent recurrences ----
  // L1(tau): gemmA(tau) | ctrlcat(tau-1) | heads(tau-2) | vt(tau-1) | xgt(tau)
  // L2(tau): scores(tau-1) | lstm(tau) | vtsum(tau-1)
  for(int tau=0; tau<=33; ++tau){
    int tG = (tau < 32) ? tau : -1;
    int tV = (tau >= 1 && tau <= 32) ? tau-1 : -1;
    int tH = (tau >= 2) ? tau-2 : -1;
    const float* hprev = (tau == 0) ? h0 : hbuf + (size_t)((tau-1)&1)*65536;
    const float* hv    = (tV >= 0) ? hbuf + (size_t)(tV&1)*65536 : hbuf;
    float* ctrlW       = ctrlP + (size_t)((tV >= 0 ? tV : 0)&1)*262144;
    float* vtpW        = vtp   + (size_t)((tV >= 0 ? tV : 0)&1)*131072;
    const float* ctrlH = ctrlP + (size_t)((tH >= 0 ? tH : 0)&1)*262144;
    k_L1<<<608,256,0,stream>>>(hprev, W_hh, gparts, tG,
                               hv, W_out, W_head, ctrlW, vtpW, tV,
                               memC, ctrlH, b_head, candW, candR, statsB,
                               reads_all, tH,
                               x, W_ih, b_ih, b_hh, xgp);
    if(tau <= 32){
      int tL = (tau < 32) ? tau : -1;
      int tS = (tau >= 1) ? tau-1 : -1;
      float* hout        = hbuf  + (size_t)((tL >= 0 ? tL : 0)&1)*65536;
      const float* ctrlS = ctrlP + (size_t)((tS >= 0 ? tS : 0)&1)*262144;
      const float* vtpR  = vtp   + (size_t)((tS >= 0 ? tS : 0)&1)*131072;
      k_L2<<<704,512,0,stream>>>(xgp, gparts, hout, c, tL,
                                 memC, ctrlS, b_head, candW, candR, statsB, tS,
                                 vtpR, b_out, out);
    }
  }
  // ---- final output GEMM: out += reads_all @ W_rd^T + b_rd ----
  k_outg<<<dim3(64,4),256,0,stream>>>(reads_all, W_rd, b_rd, out);
}

// Round 14
// 1384.448 us; speedup vs baseline: 1.0502x; 1.0502x over previous
//
#include <hip/hip_runtime.h>
#include <math.h>

#define DEV __device__ __forceinline__

static constexpr int B_ = 128, T_ = 32, H_ = 512;
static constexpr int S_ = 2048, M_ = 64, OUT_ = 256;
static constexpr float EPSF = 1e-8f;

DEV float sigmoidf_(float x){ return 1.0f/(1.0f+expf(-x)); }
DEV float softplusf_(float x){ return fmaxf(x,0.0f) + log1pf(expf(-fabsf(x))); }

// ---- packed candidate: (monotonic(value) << 32) | ~idx  => u64 '>' == (value desc, idx asc)
DEV unsigned long long packCand(float v, unsigned idx){
  unsigned u = __float_as_uint(v);
  unsigned m = (u & 0x80000000u) ? ~u : (u | 0x80000000u);
  return ((unsigned long long)m << 32) | (unsigned)(~idx);
}
DEV float unpackVal(unsigned long long e){
  unsigned m = (unsigned)(e >> 32);
  unsigned u = (m & 0x80000000u) ? (m & 0x7FFFFFFFu) : ~m;
  return __uint_as_float(u);
}
DEV unsigned unpackIdx(unsigned long long e){ return ~(unsigned)e; }

DEV void cswp(unsigned long long &a, unsigned long long &b){
  if(a < b){ unsigned long long t=a; a=b; b=t; }   // larger first (descending)
}
// Batcher odd-even mergesort for 8, descending
DEV void sort8(unsigned long long* L){
  cswp(L[0],L[1]); cswp(L[2],L[3]); cswp(L[4],L[5]); cswp(L[6],L[7]);
  cswp(L[0],L[2]); cswp(L[1],L[3]); cswp(L[4],L[6]); cswp(L[5],L[7]);
  cswp(L[1],L[2]); cswp(L[5],L[6]);
  cswp(L[0],L[4]); cswp(L[1],L[5]); cswp(L[2],L[6]); cswp(L[3],L[7]);
  cswp(L[2],L[4]); cswp(L[3],L[5]);
  cswp(L[1],L[2]); cswp(L[3],L[4]); cswp(L[5],L[6]);
}
// bitonic merge of 16, descending (input must be bitonic)
DEV void bmerge16(unsigned long long* C){
  #pragma unroll
  for(int i=0;i<8;i++) cswp(C[i],C[i+8]);
  #pragma unroll
  for(int g=0;g<2;g++){ int o=g*8;
    cswp(C[o+0],C[o+4]); cswp(C[o+1],C[o+5]); cswp(C[o+2],C[o+6]); cswp(C[o+3],C[o+7]); }
  #pragma unroll
  for(int g=0;g<4;g++){ int o=g*4; cswp(C[o+0],C[o+2]); cswp(C[o+1],C[o+3]); }
  #pragma unroll
  for(int g=0;g<8;g++){ int o=g*2; cswp(C[o],C[o+1]); }
}
// butterfly keep-8: each lane holds sorted-8 desc
DEV void butterfly8(unsigned long long* L, int maxMask){
  for(int mask=1; mask<=maxMask; mask<<=1){
    unsigned long long O[8], C[8];
    #pragma unroll
    for(int i=0;i<8;i++) O[i] = __shfl_xor(L[i], mask, 64);
    #pragma unroll
    for(int i=0;i<8;i++){ unsigned long long a=L[i], b=O[7-i]; C[i] = (a>b)?a:b; }
    cswp(C[0],C[4]); cswp(C[1],C[5]); cswp(C[2],C[6]); cswp(C[3],C[7]);
    cswp(C[0],C[2]); cswp(C[1],C[3]); cswp(C[4],C[6]); cswp(C[5],C[7]);
    cswp(C[0],C[1]); cswp(C[2],C[3]); cswp(C[4],C[5]); cswp(C[6],C[7]);
    #pragma unroll
    for(int i=0;i<8;i++) L[i]=C[i];
  }
}
// butterfly keep-16 over all 64 lanes (per-lane lists sorted-16 desc)
DEV void butterfly16(unsigned long long* L){
  for(int mask=1; mask<64; mask<<=1){
    unsigned long long O[16], C[16];
    #pragma unroll
    for(int i=0;i<16;i++) O[i] = __shfl_xor(L[i], mask, 64);
    #pragma unroll
    for(int i=0;i<16;i++){ unsigned long long a=L[i], b=O[15-i]; C[i] = (a>b)?a:b; }
    bmerge16(C);
    #pragma unroll
    for(int i=0;i<16;i++) L[i]=C[i];
  }
}

// ctrl partial-sum read: cp = ctrl partials (4 planes of 128x512) at current parity.
// value(jj) = sum_z cp[z][b][jj] + bhead[jj]   (jj = ctrl column - 256; jj < 453 valid)
DEV float ctrlv(const float* __restrict__ cp, int b, int jj, const float* __restrict__ bh){
  size_t o = (size_t)b*512 + jj;
  return cp[o] + cp[65536+o] + cp[131072+o] + cp[196608+o] + bh[jj];
}

// ---------------- generic fp32 GEMM  C[M,N] = A[M,K] * Bm[N,K]^T  (xg preamble) ----------------
__global__ __launch_bounds__(256)
void k_gemm64(const float* __restrict__ A, int lda,
              const float* __restrict__ Bm, int ldb,
              float* __restrict__ C, int ldc,
              int kCount,
              const float* __restrict__ bias0, const float* __restrict__ bias1)
{
  const int BM=64, BN=64, BK=16, LDT=68;
  __shared__ float As[BK*LDT];
  __shared__ float Bs[BK*LDT];
  const int m0 = blockIdx.x*BM, n0 = blockIdx.y*BN;
  const int tid = threadIdx.x;
  const int tx = tid & 15, ty = tid >> 4;
  const int kStart = blockIdx.z * kCount;
  float acc[4][4] = {};
  const int row = tid >> 2, kk = (tid & 3) * 4;
  for(int k0 = kStart; k0 < kStart + kCount; k0 += BK){
    float4 av = *(const float4*)(A  + (size_t)(m0+row)*lda + k0 + kk);
    float4 bv = *(const float4*)(Bm + (size_t)(n0+row)*ldb + k0 + kk);
    As[(kk+0)*LDT+row]=av.x; As[(kk+1)*LDT+row]=av.y; As[(kk+2)*LDT+row]=av.z; As[(kk+3)*LDT+row]=av.w;
    Bs[(kk+0)*LDT+row]=bv.x; Bs[(kk+1)*LDT+row]=bv.y; Bs[(kk+2)*LDT+row]=bv.z; Bs[(kk+3)*LDT+row]=bv.w;
    __syncthreads();
    #pragma unroll
    for(int k=0;k<BK;k++){
      float4 a = *(const float4*)&As[k*LDT + 4*ty];
      float4 b = *(const float4*)&Bs[k*LDT + 4*tx];
      acc[0][0]+=a.x*b.x; acc[0][1]+=a.x*b.y; acc[0][2]+=a.x*b.z; acc[0][3]+=a.x*b.w;
      acc[1][0]+=a.y*b.x; acc[1][1]+=a.y*b.y; acc[1][2]+=a.y*b.z; acc[1][3]+=a.y*b.w;
      acc[2][0]+=a.z*b.x; acc[2][1]+=a.z*b.y; acc[2][2]+=a.z*b.z; acc[2][3]+=a.z*b.w;
      acc[3][0]+=a.w*b.x; acc[3][1]+=a.w*b.y; acc[3][2]+=a.w*b.z; acc[3][3]+=a.w*b.w;
    }
    __syncthreads();
  }
  float* Cz = C + (size_t)blockIdx.z * (size_t)gridDim.x * BM * (size_t)ldc;
  #pragma unroll
  for(int i=0;i<4;i++){
    int m = m0 + 4*ty + i;
    int n = n0 + 4*tx;
    float4 o; o.x=acc[i][0]; o.y=acc[i][1]; o.z=acc[i][2]; o.w=acc[i][3];
    if(bias0){
      o.x += bias0[n]+bias1[n];     o.y += bias0[n+1]+bias1[n+1];
      o.z += bias0[n+2]+bias1[n+2]; o.w += bias0[n+3]+bias1[n+3];
    }
    *(float4*)(Cz + (size_t)m*ldc + n) = o;
  }
}

// ---------------- pipeline launch 1 (256 thr, 480 blocks) ----------------
// blk 0..255  : gemmA(tG)    — gparts = h(tG-1) @ W_hh^T, split-K x4
// blk 256..319: ctrlcat(tV)  — ctrl partials (4 z-planes of [128][512]), split-K x4
// blk 320..447: heads(tH)    — write head + mem update + read heads -> reads_all
// blk 448..479: vt(tV)       — vt partials (4 z-planes of [128][256]), split-K x4
__global__ __launch_bounds__(256)
void k_L1(const float* __restrict__ hprev, const float* __restrict__ Whh,
          float* __restrict__ gparts, int tG,
          const float* __restrict__ hv,
          const float* __restrict__ Wout, const float* __restrict__ Whead,
          float* __restrict__ ctrlW, float* __restrict__ vtpW, int tV,
          float* __restrict__ memC, const float* __restrict__ ctrlH,
          const float* __restrict__ bhead,
          const unsigned long long* __restrict__ candW,
          const unsigned long long* __restrict__ candR,
          const float* __restrict__ statsB,
          float* __restrict__ readsAll, int tH)
{
  __shared__ __align__(16) float smem[2304];
  const int blk = blockIdx.x, tid = threadIdx.x;

  if(blk < 256){
    // ---- gemmA role (round-11-verified) ----
    if(tG < 0) return;
    float* As = smem;
    float* Bs = smem + 1088;
    const int z = blk >> 6, rem = blk & 63;
    const int m0 = (rem & 1)*64, n0 = (rem >> 1)*64;
    const int tx = tid & 15, ty = tid >> 4;
    float acc[4][4] = {};
    const int row = tid >> 2, kq = (tid & 3)*4;
    const int kStart = z*128;
    for(int k0 = kStart; k0 < kStart + 128; k0 += 16){
      float4 av = *(const float4*)(hprev + (size_t)(m0+row)*512 + k0 + kq);
      float4 bv = *(const float4*)(Whh   + (size_t)(n0+row)*512 + k0 + kq);
      As[(kq+0)*68+row]=av.x; As[(kq+1)*68+row]=av.y; As[(kq+2)*68+row]=av.z; As[(kq+3)*68+row]=av.w;
      Bs[(kq+0)*68+row]=bv.x; Bs[(kq+1)*68+row]=bv.y; Bs[(kq+2)*68+row]=bv.z; Bs[(kq+3)*68+row]=bv.w;
      __syncthreads();
      #pragma unroll
      for(int k=0;k<16;k++){
        float4 a = *(const float4*)&As[k*68 + 4*ty];
        float4 b = *(const float4*)&Bs[k*68 + 4*tx];
        acc[0][0]+=a.x*b.x; acc[0][1]+=a.x*b.y; acc[0][2]+=a.x*b.z; acc[0][3]+=a.x*b.w;
        acc[1][0]+=a.y*b.x; acc[1][1]+=a.y*b.y; acc[1][2]+=a.y*b.z; acc[1][3]+=a.y*b.w;
        acc[2][0]+=a.z*b.x; acc[2][1]+=a.z*b.y; acc[2][2]+=a.z*b.z; acc[2][3]+=a.z*b.w;
        acc[3][0]+=a.w*b.x; acc[3][1]+=a.w*b.y; acc[3][2]+=a.w*b.z; acc[3][3]+=a.w*b.w;
      }
      __syncthreads();
    }
    float* Cz = gparts + (size_t)z*262144;
    #pragma unroll
    for(int i=0;i<4;i++){
      float4 o; o.x=acc[i][0]; o.y=acc[i][1]; o.z=acc[i][2]; o.w=acc[i][3];
      *(float4*)(Cz + (size_t)(m0+4*ty+i)*2048 + n0 + 4*tx) = o;
    }
    return;
  }

  if(blk < 320){
    // ---- ctrlcat role: ctrl partials, split-K x4 (no bias; consumer adds bhead) ----
    if(tV < 0) return;
    float* As = smem;
    float* Bs = smem + 1088;
    const int g = blk - 256;                 // 0..63
    const int z = g >> 4, rem = g & 15;
    const int m0 = (rem & 1)*64;
    const int jj0 = (rem >> 1)*64;           // ctrl-local col base (0..448)
    const int tx = tid & 15, ty = tid >> 4;
    float acc[4][4] = {};
    const int row = tid >> 2, kq = (tid & 3)*4;
    const int kStart = z*128;
    const int jr = jj0 + row;
    const float* Bsrc = (jr < 453) ? (Whead + (size_t)jr*512) : nullptr;
    for(int k0 = kStart; k0 < kStart + 128; k0 += 16){
      float4 av = *(const float4*)(hv + (size_t)(m0+row)*512 + k0 + kq);
      float4 bv = make_float4(0.f,0.f,0.f,0.f);
      if(Bsrc) bv = *(const float4*)(Bsrc + k0 + kq);
      As[(kq+0)*68+row]=av.x; As[(kq+1)*68+row]=av.y; As[(kq+2)*68+row]=av.z; As[(kq+3)*68+row]=av.w;
      Bs[(kq+0)*68+row]=bv.x; Bs[(kq+1)*68+row]=bv.y; Bs[(kq+2)*68+row]=bv.z; Bs[(kq+3)*68+row]=bv.w;
      __syncthreads();
      #pragma unroll
      for(int k=0;k<16;k++){
        float4 a = *(const float4*)&As[k*68 + 4*ty];
        float4 b = *(const float4*)&Bs[k*68 + 4*tx];
        acc[0][0]+=a.x*b.x; acc[0][1]+=a.x*b.y; acc[0][2]+=a.x*b.z; acc[0][3]+=a.x*b.w;
        acc[1][0]+=a.y*b.x; acc[1][1]+=a.y*b.y; acc[1][2]+=a.y*b.z; acc[1][3]+=a.y*b.w;
        acc[2][0]+=a.z*b.x; acc[2][1]+=a.z*b.y; acc[2][2]+=a.z*b.z; acc[2][3]+=a.z*b.w;
        acc[3][0]+=a.w*b.x; acc[3][1]+=a.w*b.y; acc[3][2]+=a.w*b.z; acc[3][3]+=a.w*b.w;
      }
      __syncthreads();
    }
    float* Cz = ctrlW + (size_t)z*65536;     // z-plane: 128*512
    #pragma unroll
    for(int i=0;i<4;i++){
      float4 o; o.x=acc[i][0]; o.y=acc[i][1]; o.z=acc[i][2]; o.w=acc[i][3];
      *(float4*)(Cz + (size_t)(m0+4*ty+i)*512 + jj0 + 4*tx) = o;
    }
    return;
  }

  if(blk < 448){
    // ---- heads role (round-10-verified body; v[] reads via ctrl partial sum) ----
    if(tH < 0) return;
    float* kr     = smem;                    // 256 (16B-aligned)
    float* nv     = smem + 256;              // 512
    float* oldrow = smem + 768;              // 512
    float* er     = smem + 1280;             // 64
    float* ad     = smem + 1344;             // 64
    float* coefR  = smem + 1408;             // 4
    int*   widx   = (int*)(smem + 1412);     // 8
    float* wval   = smem + 1420;             // 8

    const int b = blk - 320;
    const int lane = tid & 63, wave = tid >> 6;
    const size_t memb = (size_t)b*(size_t)S_*M_;

    kr[tid] = tanhf(ctrlv(ctrlH, b, tid, bhead));                    // v[256+tid]
    if(tid < 64){
      er[tid] = sigmoidf_(ctrlv(ctrlH, b, 325+tid, bhead));          // v[581+tid]
      ad[tid] = tanhf(ctrlv(ctrlH, b, 389+tid, bhead));              // v[645+tid]
    }
    __syncthreads();

    if(wave == 0){
      float smx[4], ssm[4];
      #pragma unroll
      for(int c2=0;c2<4;c2++){
        const float* st = statsB + (((size_t)b*4 + c2)*5 + 4)*2;
        smx[c2] = st[0]; ssm[c2] = st[1];
      }
      float mxw = fmaxf(fmaxf(smx[0],smx[1]), fmaxf(smx[2],smx[3]));
      float Zw = ssm[0]*expf(smx[0]-mxw) + ssm[1]*expf(smx[1]-mxw)
               + ssm[2]*expf(smx[2]-mxw) + ssm[3]*expf(smx[3]-mxw);
      unsigned long long L[8];
      L[0] = (lane < 32) ? candW[((size_t)b*4 + (lane>>3))*8 + (lane&7)] : 0ULL;
      #pragma unroll
      for(int j=1;j<8;j++) L[j] = 0ULL;
      butterfly8(L, 16);
      if(lane == 0){
        float invZ = 1.0f / Zw;
        #pragma unroll
        for(int p=0;p<8;p++){
          widx[p] = (int)unpackIdx(L[p]);
          wval[p] = expf(unpackVal(L[p]) - mxw) * invZ;
        }
      }
    } else if(wave == 1 && lane < 4){
      float s = 0.f;
      #pragma unroll
      for(int m=0;m<64;m++){ float x2 = kr[lane*64+m]; s += x2*x2; }
      coefR[lane] = softplusf_(ctrlv(ctrlH, b, 256+lane, bhead)) / fmaxf(sqrtf(s), EPSF);
    }
    __syncthreads();

    {
      #pragma unroll
      for(int p=0;p<2;p++){
        int idx = tid + p*256;
        int jj = idx >> 6, mm = idx & 63;
        int s = widx[jj];
        float w = wval[jj];
        size_t ptr = memb + (size_t)s*M_ + mm;
        float old = memC[ptr];
        oldrow[jj*64+mm] = old;
        float x2 = old * (1.0f - w*er[mm]) + w*ad[mm];
        memC[ptr] = x2;
        nv[jj*64+mm] = x2;
      }
    }
    __syncthreads();

    {
      const int r = wave;
      const int sW = lane & 7, g = lane >> 3;
      const float4* nv4 = (const float4*)nv;
      const float4* ov4 = (const float4*)oldrow;
      const float4* kr4 = (const float4*)kr;
      float4 na = nv4[sW*16 + g*2], nb2 = nv4[sW*16 + g*2 + 1];
      float4 oa = ov4[sW*16 + g*2], ob = ov4[sW*16 + g*2 + 1];
      float4 ka = kr4[r*16  + g*2], kb = kr4[r*16  + g*2 + 1];
      float dot = na.x*ka.x + na.y*ka.y + na.z*ka.z + na.w*ka.w
                + nb2.x*kb.x + nb2.y*kb.y + nb2.z*kb.z + nb2.w*kb.w;
      float n2  = na.x*na.x + na.y*na.y + na.z*na.z + na.w*na.w
                + nb2.x*nb2.x + nb2.y*nb2.y + nb2.z*nb2.z + nb2.w*nb2.w;
      float odot= oa.x*ka.x + oa.y*ka.y + oa.z*ka.z + oa.w*ka.w
                + ob.x*kb.x + ob.y*kb.y + ob.z*kb.z + ob.w*kb.w;
      float on2 = oa.x*oa.x + oa.y*oa.y + oa.z*oa.z + oa.w*oa.w
                + ob.x*ob.x + ob.y*ob.y + ob.z*ob.z + ob.w*ob.w;
      #pragma unroll
      for(int mask=8; mask<64; mask<<=1){
        dot  += __shfl_xor(dot,  mask, 64);
        n2   += __shfl_xor(n2,   mask, 64);
        odot += __shfl_xor(odot, mask, 64);
        on2  += __shfl_xor(on2,  mask, 64);
      }
      float fixv = coefR[r] * dot  / fmaxf(sqrtf(n2),  EPSF);
      float oldv = coefR[r] * odot / fmaxf(sqrtf(on2), EPSF);
      int myw = widx[sW];

      float scx[4], scs[4];
      #pragma unroll
      for(int c2=0;c2<4;c2++){
        const float* st = statsB + (((size_t)b*4 + c2)*5 + r)*2;
        scx[c2] = st[0]; scs[c2] = st[1];
      }
      float mxp = fmaxf(fmaxf(scx[0],scx[1]), fmaxf(scx[2],scx[3]));

      unsigned long long L[8];
      {
        int c2 = lane >> 4, rank = lane & 15;
        unsigned long long eA = candR[(((size_t)b*4 + c2)*4 + r)*16 + rank];
        unsigned idxA = unpackIdx(eA);
        bool kill = false;
        #pragma unroll
        for(int p=0;p<8;p++) kill = kill || (idxA == (unsigned)widx[p]);
        if(kill) eA = 0ULL;
        unsigned long long eB = (lane < 8) ? packCand(fixv, (unsigned)myw) : 0ULL;
        L[0] = (eA > eB) ? eA : eB;
        L[1] = (eA > eB) ? eB : eA;
        #pragma unroll
        for(int j2=2;j2<8;j2++) L[j2] = 0ULL;
      }
      butterfly8(L, 32);

      float mxS = fmaxf(mxp, unpackVal(L[0]));
      float Zp = scs[0]*expf(scx[0]-mxS) + scs[1]*expf(scx[1]-mxS)
               + scs[2]*expf(scx[2]-mxS) + scs[3]*expf(scx[3]-mxS);
      float adj = (lane < 8) ? (expf(fixv - mxS) - expf(oldv - mxS)) : 0.f;
      #pragma unroll
      for(int mask=1; mask<64; mask<<=1) adj += __shfl_xor(adj, mask, 64);
      float invZ = 1.0f / (Zp + adj);

      float acc = 0.f;
      #pragma unroll
      for(int p=0;p<8;p++){
        float w = expf(unpackVal(L[p]) - mxS) * invZ;
        int si = (int)unpackIdx(L[p]);
        acc += w * memC[memb + (size_t)si*M_ + lane];
      }
      readsAll[((size_t)b*T_ + tH)*256 + r*64 + lane] = acc;
    }
    return;
  }

  // ---- vt role: vt partials, split-K x4 (no bias; vtsum adds bout) ----
  if(tV < 0) return;
  {
    float* As = smem;
    float* Bs = smem + 1088;
    const int g = blk - 448;                 // 0..31
    const int z = g >> 3, rem = g & 7;
    const int m0 = (rem & 1)*64, n0 = (rem >> 1)*64;
    const int tx = tid & 15, ty = tid >> 4;
    float acc[4][4] = {};
    const int row = tid >> 2, kq = (tid & 3)*4;
    const int kStart = z*128;
    const float* Bsrc = Wout + (size_t)(n0+row)*512;
    for(int k0 = kStart; k0 < kStart + 128; k0 += 16){
      float4 av = *(const float4*)(hv + (size_t)(m0+row)*512 + k0 + kq);
      float4 bv = *(const float4*)(Bsrc + k0 + kq);
      As[(kq+0)*68+row]=av.x; As[(kq+1)*68+row]=av.y; As[(kq+2)*68+row]=av.z; As[(kq+3)*68+row]=av.w;
      Bs[(kq+0)*68+row]=bv.x; Bs[(kq+1)*68+row]=bv.y; Bs[(kq+2)*68+row]=bv.z; Bs[(kq+3)*68+row]=bv.w;
      __syncthreads();
      #pragma unroll
      for(int k=0;k<16;k++){
        float4 a = *(const float4*)&As[k*68 + 4*ty];
        float4 b = *(const float4*)&Bs[k*68 + 4*tx];
        acc[0][0]+=a.x*b.x; acc[0][1]+=a.x*b.y; acc[0][2]+=a.x*b.z; acc[0][3]+=a.x*b.w;
        acc[1][0]+=a.y*b.x; acc[1][1]+=a.y*b.y; acc[1][2]+=a.y*b.z; acc[1][3]+=a.y*b.w;
        acc[2][0]+=a.z*b.x; acc[2][1]+=a.z*b.y; acc[2][2]+=a.z*b.z; acc[2][3]+=a.z*b.w;
        acc[3][0]+=a.w*b.x; acc[3][1]+=a.w*b.y; acc[3][2]+=a.w*b.z; acc[3][3]+=a.w*b.w;
      }
      __syncthreads();
    }
    float* Cz = vtpW + (size_t)z*32768;      // z-plane: 128*256
    #pragma unroll
    for(int i=0;i<4;i++){
      float4 o; o.x=acc[i][0]; o.y=acc[i][1]; o.z=acc[i][2]; o.w=acc[i][3];
      *(float4*)(Cz + (size_t)(m0+4*ty+i)*256 + n0 + 4*tx) = o;
    }
  }
}

// ---------------- pipeline launch 2 (512 thr, 704 blocks) ----------------
// blk 0..511  : scores(tS) — round-10-verified body, v[] via ctrl partial sum
// blk 512..639: lstm(tL)   — gate sum + cell update -> hout
// blk 640..703: vtsum(tS)  — out[b,tS,:] = sum_z vtp[z] + bout
__global__ __launch_bounds__(512)
void k_L2(const float* __restrict__ xg, const float* __restrict__ gp,
          float* __restrict__ hout, float* __restrict__ c, int tL,
          const float* __restrict__ memC, const float* __restrict__ ctrlS,
          const float* __restrict__ bhead,
          unsigned long long* __restrict__ candW,
          unsigned long long* __restrict__ candR,
          float* __restrict__ statsB, int tS,
          const float* __restrict__ vtpR, const float* __restrict__ bout,
          float* __restrict__ out)
{
  __shared__ float smem[2896];
  const int blk = blockIdx.x, tid = threadIdx.x;

  if(blk >= 640){
    // ---- vtsum role ----
    if(tS < 0) return;
    int idx = (blk - 640)*512 + tid;         // 0..32767
    int b = idx >> 8, n = idx & 255;
    float s = vtpR[(size_t)b*256+n] + vtpR[32768 + (size_t)b*256+n]
            + vtpR[65536 + (size_t)b*256+n] + vtpR[98304 + (size_t)b*256+n];
    out[((size_t)b*T_ + tS)*OUT_ + n] = s + bout[n];
    return;
  }
  if(blk >= 512){
    // ---- lstm role ----
    if(tL < 0) return;
    int idx = (blk - 512)*512 + tid;         // 0..65535
    int b = idx >> 9, j = idx & 511;
    const float* xr = xg + ((size_t)b*T_ + tL)*(size_t)(4*H_);
    float gi = xr[j], gf = xr[512+j], gg = xr[1024+j], go = xr[1536+j];
    #pragma unroll
    for(int s4=0;s4<4;s4++){
      const float* pr = gp + ((size_t)s4*B_ + b)*(size_t)(4*H_);
      gi += pr[j]; gf += pr[512+j]; gg += pr[1024+j]; go += pr[1536+j];
    }
    float cc = sigmoidf_(gf)*c[idx] + sigmoidf_(gi)*tanhf(gg);
    float hh = sigmoidf_(go)*tanhf(cc);
    c[idx] = cc; hout[idx] = hh;
    return;
  }

  // ---- scores role ----
  if(tS < 0) return;
  float* kk   = smem;          // 320
  float* coef = smem + 320;    // 8 (5 used)
  float* tile = smem + 328;    // 5*512
  const int b = blk >> 2, ch = blk & 3;
  const int lane = tid & 63, wid = tid >> 6;
  if(tid < 256) kk[tid] = tanhf(ctrlv(ctrlS, b, tid, bhead));          // kr: v[256+tid]
  else if(tid < 320) kk[tid] = tanhf(ctrlv(ctrlS, b, tid+4, bhead));   // kw: jj = 260..323
  __syncthreads();
  if(tid < 5){
    float s = 0.f;
    #pragma unroll
    for(int m=0;m<64;m++){ float x2 = kk[tid*64+m]; s += x2*x2; }
    float beta = softplusf_( tid<4 ? ctrlv(ctrlS, b, 256+tid, bhead)
                                   : ctrlv(ctrlS, b, 324, bhead) );
    coef[tid] = beta / fmaxf(sqrtf(s), EPSF);
  }
  __syncthreads();

  {
    const int s = ch*512 + tid;
    const float4* row = (const float4*)(memC + ((size_t)b*S_ + s)*M_);
    float nrm=0.f, d0=0.f, d1=0.f, d2=0.f, d3=0.f, dw=0.f;
    #pragma unroll
    for(int r4=0;r4<16;r4++){
      float4 xa = row[r4];
      float av[4] = {xa.x,xa.y,xa.z,xa.w};
      #pragma unroll
      for(int j=0;j<4;j++){
        const int m = r4*4+j;
        float a = av[j];
        nrm += a*a;
        d0 += a*kk[m];     d1 += a*kk[64+m]; d2 += a*kk[128+m];
        d3 += a*kk[192+m]; dw += a*kk[256+m];
      }
    }
    float inv = 1.0f / fmaxf(sqrtf(nrm), EPSF);
    tile[0*512+tid] = coef[0]*d0*inv;
    tile[1*512+tid] = coef[1]*d1*inv;
    tile[2*512+tid] = coef[2]*d2*inv;
    tile[3*512+tid] = coef[3]*d3*inv;
    tile[4*512+tid] = coef[4]*dw*inv;
  }
  __syncthreads();

  if(wid < 4){
    unsigned long long L[16];
    #pragma unroll
    for(int j=0;j<8;j++){
      int i = lane + j*64;
      L[j] = packCand(tile[wid*512 + i], (unsigned)(ch*512 + i));
    }
    sort8(L);
    #pragma unroll
    for(int j=8;j<16;j++) L[j] = 0ULL;
    butterfly16(L);
    if(lane == 0){
      unsigned long long* dst = candR + (((size_t)b*4 + ch)*4 + wid)*16;
      #pragma unroll
      for(int j=0;j<16;j++) dst[j] = L[j];
    }
  } else if(wid == 4){
    unsigned long long L[8];
    #pragma unroll
    for(int j=0;j<8;j++){
      int i = lane + j*64;
      L[j] = packCand(tile[4*512 + i], (unsigned)(ch*512 + i));
    }
    sort8(L);
    butterfly8(L, 32);
    if(lane == 0){
      unsigned long long* dst = candW + ((size_t)b*4 + ch)*8;
      #pragma unroll
      for(int j=0;j<8;j++) dst[j] = L[j];
    }
  } else {
    int h0 = (wid==5) ? 0 : (wid==6) ? 2 : 4;
    int nh = (wid==7) ? 1 : 2;
    for(int q=0;q<nh;q++){
      int h = h0 + q;
      float x2[8];
      #pragma unroll
      for(int j=0;j<8;j++) x2[j] = tile[h*512 + lane + j*64];
      float mx = x2[0];
      #pragma unroll
      for(int j=1;j<8;j++) mx = fmaxf(mx, x2[j]);
      #pragma unroll
      for(int mask=1; mask<64; mask<<=1) mx = fmaxf(mx, __shfl_xor(mx, mask, 64));
      float sm = 0.f;
      #pragma unroll
      for(int j=0;j<8;j++) sm += expf(x2[j]-mx);
      #pragma unroll
      for(int mask=1; mask<64; mask<<=1) sm += __shfl_xor(sm, mask, 64);
      if(lane == 0){
        float* st = statsB + (((size_t)b*4 + ch)*5 + h)*2;
        st[0] = mx; st[1] = sm;
      }
    }
  }
}

// ---------------- final: out += reads_all @ W_rd^T + b_rd  (vt already in out) ----------------
__global__ __launch_bounds__(256)
void k_outg(const float* __restrict__ A,             // reads_all [4096,256]
            const float* __restrict__ Wrd,           // [256,256]
            const float* __restrict__ brd,
            float* __restrict__ out)
{
  const int BK=16, LDT=68;
  __shared__ float As[BK*LDT];
  __shared__ float Bs[BK*LDT];
  const int m0 = blockIdx.x*64, n0 = blockIdx.y*64;
  const int tid = threadIdx.x;
  const int tx = tid & 15, ty = tid >> 4;
  float acc[4][4] = {};
  const int row = tid >> 2, kk = (tid & 3) * 4;
  for(int k0 = 0; k0 < 256; k0 += BK){
    float4 av = *(const float4*)(A   + (size_t)(m0+row)*256 + k0 + kk);
    float4 bv = *(const float4*)(Wrd + (size_t)(n0+row)*256 + k0 + kk);
    As[(kk+0)*LDT+row]=av.x; As[(kk+1)*LDT+row]=av.y; As[(kk+2)*LDT+row]=av.z; As[(kk+3)*LDT+row]=av.w;
    Bs[(kk+0)*LDT+row]=bv.x; Bs[(kk+1)*LDT+row]=bv.y; Bs[(kk+2)*LDT+row]=bv.z; Bs[(kk+3)*LDT+row]=bv.w;
    __syncthreads();
    #pragma unroll
    for(int k=0;k<BK;k++){
      float4 a = *(const float4*)&As[k*LDT + 4*ty];
      float4 b = *(const float4*)&Bs[k*LDT + 4*tx];
      acc[0][0]+=a.x*b.x; acc[0][1]+=a.x*b.y; acc[0][2]+=a.x*b.z; acc[0][3]+=a.x*b.w;
      acc[1][0]+=a.y*b.x; acc[1][1]+=a.y*b.y; acc[1][2]+=a.y*b.z; acc[1][3]+=a.y*b.w;
      acc[2][0]+=a.z*b.x; acc[2][1]+=a.z*b.y; acc[2][2]+=a.z*b.z; acc[2][3]+=a.z*b.w;
      acc[3][0]+=a.w*b.x; acc[3][1]+=a.w*b.y; acc[3][2]+=a.w*b.z; acc[3][3]+=a.w*b.w;
    }
    __syncthreads();
  }
  const int nb = n0 + 4*tx;
  float4 bb = *(const float4*)(brd + nb);
  #pragma unroll
  for(int i=0;i<4;i++){
    int m = m0 + 4*ty + i;
    float4 vt = *(const float4*)(out + (size_t)m*256 + nb);
    float4 o;
    o.x = acc[i][0] + bb.x + vt.x;
    o.y = acc[i][1] + bb.y + vt.y;
    o.z = acc[i][2] + bb.z + vt.z;
    o.w = acc[i][3] + bb.w + vt.w;
    *(float4*)(out + (size_t)m*256 + nb) = o;
  }
}

// ---------------- host ----------------
extern "C" void kernel_launch(void* const* d_in, const int* in_sizes, int n_in,
                              void* d_out, int out_size, void* d_ws, size_t ws_size,
                              hipStream_t stream)
{
  const float* x     = (const float*)d_in[0];
  const float* h0    = (const float*)d_in[1];
  const float* c0    = (const float*)d_in[2];
  const float* mem0  = (const float*)d_in[3];
  const float* W_ih  = (const float*)d_in[4];
  const float* W_hh  = (const float*)d_in[5];
  const float* b_ih  = (const float*)d_in[6];
  const float* b_hh  = (const float*)d_in[7];
  const float* W_out = (const float*)d_in[8];
  const float* b_out = (const float*)d_in[9];
  const float* W_rd  = (const float*)d_in[10];
  const float* b_rd  = (const float*)d_in[11];
  const float* W_head= (const float*)d_in[12];
  const float* b_head= (const float*)d_in[13];
  // d_in[14] = K (int) — fixed at 8 by the problem setup; hard-coded in k_L1 heads role.
  float* out = (float*)d_out;

  float* ws     = (float*)d_ws;
  float* memC   = ws;                    // 16,777,216  (slot-major [B,S,M])
  float* xg     = memC  + 16777216;      //  8,388,608
  float* hbuf   = xg    + 8388608;       //    131,072  (h ping-pong x2)
  float* c      = hbuf  + 131072;        //     65,536
  float* gparts = c     + 65536;         //  1,048,576
  float* ctrlP  = gparts+ 1048576;       //    524,288  (2 parity x 4 z x 128 x 512)
  float* vtp    = ctrlP + 524288;        //    262,144  (2 parity x 4 z x 128 x 256)
  float* reads_all = vtp + 262144;       //  1,048,576
  unsigned long long* candW = (unsigned long long*)(reads_all + 1048576); // 4096 u64
  unsigned long long* candR = candW + 4096;                               // 32768 u64
  float* statsB = (float*)(candR + 32768);                                // 5,120
  const size_t need = (size_t)(28324864) * sizeof(float);
  if(ws_size < need) return;  // 113.3 MB (<= 113.77 MB proven capacity)

  hipMemcpyAsync(c, c0, 65536*sizeof(float), hipMemcpyDeviceToDevice, stream);
  hipMemcpyAsync(memC, mem0, (size_t)16777216*sizeof(float), hipMemcpyDeviceToDevice, stream);
  // xg[b*T+t, :] = x @ W_ih^T + (b_ih+b_hh)
  k_gemm64<<<dim3(64,32,1),256,0,stream>>>(x,256, W_ih,256, xg,2048, 256, b_ih,b_hh);

  // ---- 2-deep software pipeline over the two independent recurrences ----
  for(int tau=0; tau<=33; ++tau){
    int tG = (tau < 32) ? tau : -1;
    int tV = (tau >= 1 && tau <= 32) ? tau-1 : -1;
    int tH = (tau >= 2) ? tau-2 : -1;
    const float* hprev = (tau == 0) ? h0 : hbuf + (size_t)((tau-1)&1)*65536;
    const float* hv    = (tV >= 0) ? hbuf + (size_t)(tV&1)*65536 : hbuf;
    float* ctrlW       = ctrlP + (size_t)((tV >= 0 ? tV : 0)&1)*262144;
    float* vtpW        = vtp   + (size_t)((tV >= 0 ? tV : 0)&1)*131072;
    const float* ctrlH = ctrlP + (size_t)((tH >= 0 ? tH : 0)&1)*262144;
    k_L1<<<480,256,0,stream>>>(hprev, W_hh, gparts, tG,
                               hv, W_out, W_head, ctrlW, vtpW, tV,
                               memC, ctrlH, b_head, candW, candR, statsB,
                               reads_all, tH);
    if(tau <= 32){
      int tL = (tau < 32) ? tau : -1;
      int tS = (tau >= 1) ? tau-1 : -1;
      float* hout        = hbuf  + (size_t)((tL >= 0 ? tL : 0)&1)*65536;
      const float* ctrlS = ctrlP + (size_t)((tS >= 0 ? tS : 0)&1)*262144;
      const float* vtpR  = vtp   + (size_t)((tS >= 0 ? tS : 0)&1)*131072;
      k_L2<<<704,512,0,stream>>>(xg, gparts, hout, c, tL,
                                 memC, ctrlS, b_head, candW, candR, statsB, tS,
                                 vtpR, b_out, out);
    }
  }
  // ---- final output GEMM: out += reads_all @ W_rd^T + b_rd ----
  k_outg<<<dim3(64,4),256,0,stream>>>(reads_all, W_rd, b_rd, out);
}